// Round 12
// baseline (83.788 us; speedup 1.0000x reference)
//
#include <hip/hip_runtime.h>

namespace {
constexpr int N_ = 8, C_ = 32, H_ = 256, W_ = 512, DISP_ = 25;
constexpr int CH = H_ * W_;  // elements between channels / disparities
constexpr int NSS = C_ / 2;  // 16 supersteps of 2 channels
}

typedef const __attribute__((address_space(1))) void gas_t;  // global
typedef __attribute__((address_space(3))) void las_t;        // LDS

// 4-way disparity split (small acc => high occupancy, from r5) combined with
// global_load_lds staging + counted-vmcnt depth-2 pipeline (compulsory HBM
// traffic, from r9-11). r11 post-mortem: acc-52 config resides only ~11
// waves/CU and VALUBusy pins at 44%; r5 showed acc-28 resides 18+ waves but
// died on 4x redundant GLOBAL window reads -- LDS staging fixes exactly that.
//
// 512 threads/block = one (n,h) row, grid = N*H.
//   t = tid & 127 -> 4 output columns (w0 = 4t)
//   G = tid >> 7  -> disparity group (wave-uniform):
//     G0: i in [0,7) OFF +4 | G1: [7,13) OFF 0 | G2: [13,19) OFF -8
//     G3: [19,25) OFF -12      (window m = cw+12-OFF-i, compile-time in [0,12))
//   wv = tid >> 6 -> staging role: arr = wv&1 (x/y), chsel = (wv>>1)&1
//     (channel within superstep), half = wv>>2 (256-float half of row).
// Each wave issues ONE global_load_lds_dwordx4 per superstep (wave-uniform
// LDS base + lane*16 == linear layout). Buffer (2048 floats): ch0
// x[0,512) y[512,1024) | ch1 x[1024,1536) y[1536,2048); 4 buffers = 32 KB.
// Steady state: vmcnt(1) completes superstep s's load (leaves s+1's in
// flight); s_barrier; issue stage(s+2); compute s from LDS.
// Registers: acc 28 + temps 16 + addr ~20 = ~75 << 128 cap of (512,4)
// (spill rule est <= cap-40; WRITE_SIZE is the spill detector).
template <int G>
__device__ __forceinline__ void body(const float* __restrict__ sbase,
                                     float* __restrict__ op, float* lds,
                                     int lds_woff, const int* yoff, int w0) {
  constexpr int I0 = (G == 0) ? 0 : (G == 1) ? 7 : (G == 2) ? 13 : 19;
  constexpr int NI = (G == 0) ? 7 : 6;
  constexpr int OFF = (G == 0) ? 4 : (G == 1) ? 0 : (G == 2) ? -8 : -12;

  float acc[NI][4];
#pragma unroll
  for (int il = 0; il < NI; ++il)
#pragma unroll
    for (int cw = 0; cw < 4; ++cw) acc[il][cw] = 0.0f;

#define STAGE(s)                                                          \
  __builtin_amdgcn_global_load_lds(                                       \
      (gas_t*)(sbase + (size_t)(2 * (s)) * CH),                           \
      (las_t*)(lds + ((s)&3) * 2048 + lds_woff), 16, 0, 0)

#define COMPUTE1(base)                                                    \
  do {                                                                    \
    const float* lx = (base);       /* x row (512 floats) */              \
    const float* ly = (base) + 512; /* y row (512 floats) */              \
    const float4 xv = *reinterpret_cast<const float4*>(lx + w0);          \
    float4 yv[3];                                                         \
    _Pragma("unroll") for (int k = 0; k < 3; ++k) yv[k] =                 \
        *reinterpret_cast<const float4*>(ly + yoff[k]);                   \
    const float xs[4] = {xv.x, xv.y, xv.z, xv.w};                         \
    const float ywin[12] = {yv[0].x, yv[0].y, yv[0].z, yv[0].w,           \
                            yv[1].x, yv[1].y, yv[1].z, yv[1].w,           \
                            yv[2].x, yv[2].y, yv[2].z, yv[2].w};          \
    _Pragma("unroll") for (int il = 0; il < NI; ++il) {                   \
      _Pragma("unroll") for (int cw = 0; cw < 4; ++cw) {                  \
        acc[il][cw] += fabsf(xs[cw] - ywin[cw + 12 - OFF - (I0 + il)]);   \
      }                                                                   \
    }                                                                     \
  } while (0)

#define COMPUTE2(s)                                                       \
  do {                                                                    \
    const float* bp = lds + ((s)&3) * 2048;                               \
    COMPUTE1(bp);                                                         \
    COMPUTE1(bp + 1024);                                                  \
  } while (0)

  // Prologue: two supersteps in flight (1 load/wave each).
  STAGE(0);
  STAGE(1);

#pragma unroll 1
  for (int s = 0; s < NSS - 1; ++s) {
    // Complete superstep s's load; leave s+1's in flight.
    asm volatile("s_waitcnt vmcnt(1)" ::: "memory");
    __builtin_amdgcn_s_barrier();
    if (s + 2 < NSS) STAGE(s + 2);
    COMPUTE2(s);
  }
  // Final superstep: drain fully.
  asm volatile("s_waitcnt vmcnt(0)" ::: "memory");
  __builtin_amdgcn_s_barrier();
  COMPUTE2(NSS - 1);

#undef STAGE
#undef COMPUTE1
#undef COMPUTE2

  // Epilogue: zero out-of-overlap (w,i) pairs, coalesced float4 stores.
#pragma unroll
  for (int il = 0; il < NI; ++il) {
    const int i = I0 + il;
    const int j0 = w0 - i + 12;  // y column used by cw=0
    float4 v;
    v.x = ((unsigned)(j0 + 0) < (unsigned)W_) ? acc[il][0] : 0.0f;
    v.y = ((unsigned)(j0 + 1) < (unsigned)W_) ? acc[il][1] : 0.0f;
    v.z = ((unsigned)(j0 + 2) < (unsigned)W_) ? acc[il][2] : 0.0f;
    v.w = ((unsigned)(j0 + 3) < (unsigned)W_) ? acc[il][3] : 0.0f;
    *reinterpret_cast<float4*>(op + (size_t)i * CH) = v;
  }
}

__global__ __launch_bounds__(512, 4) void rescost_kernel(
    const float* __restrict__ x, const float* __restrict__ y,
    float* __restrict__ out) {
  __shared__ __align__(16) float lds[4 * 2048];  // 32 KB, 4 superstep buffers

  const int tid = threadIdx.x;
  const int t = tid & 127;    // column group (compute)
  const int g = tid >> 7;     // disparity group (wave-uniform)
  const int wv = tid >> 6;    // wave id = staging role (wave-uniform)
  const int lane = tid & 63;
  const int r = blockIdx.x;   // row in [0, N*H)
  const int n = r >> 8;       // H = 256
  const int h = r & (H_ - 1);
  const int w0 = t << 2;

  // Staging: wave wv stages floats [half*256, +256) of channel (2s+chsel) of
  // array arr. Global src per-lane (lane*4 floats); LDS dest = wave base
  // (+lane*16B by HW).
  const int arr = wv & 1;
  const int chsel = (wv >> 1) & 1;
  const int half = wv >> 2;
  const size_t row_base = ((size_t)n * C_ * H_ + (size_t)h) * W_;
  const float* sbase = (arr ? y : x) + row_base + (size_t)chsel * CH +
                       (half << 8) + (lane << 2);
  const int lds_woff = (chsel << 10) + (arr << 9) + (half << 8);  // floats

  // 3 clamped 16B-aligned y-window offsets; base = w0 + OFF[g]. Each float4
  // window is fully in [0,W) or fully OOB (base mult of 4); clamped windows
  // only feed epilogue-zeroed outputs. (Layout verified bit-exact in r5.)
  const int off_tab[4] = {4, 0, -8, -12};
  const int ybase = w0 + off_tab[g];
  int yoff[3];
#pragma unroll
  for (int k = 0; k < 3; ++k) {
    int idx = ybase + 4 * k;
    idx = idx < 0 ? 0 : idx;
    idx = idx > (W_ - 4) ? (W_ - 4) : idx;
    yoff[k] = idx;
  }

  float* op = out + ((size_t)n * DISP_ * H_ + (size_t)h) * W_ + w0;

  if (g == 0)
    body<0>(sbase, op, lds, lds_woff, yoff, w0);
  else if (g == 1)
    body<1>(sbase, op, lds, lds_woff, yoff, w0);
  else if (g == 2)
    body<2>(sbase, op, lds, lds_woff, yoff, w0);
  else
    body<3>(sbase, op, lds, lds_woff, yoff, w0);
}

extern "C" void kernel_launch(void* const* d_in, const int* in_sizes, int n_in,
                              void* d_out, int out_size, void* d_ws, size_t ws_size,
                              hipStream_t stream) {
  const float* x = (const float*)d_in[0];
  const float* y = (const float*)d_in[1];
  float* out = (float*)d_out;
  dim3 grid(N_ * H_);  // one (n,h) row per block
  dim3 block(512);
  hipLaunchKernelGGL(rescost_kernel, grid, block, 0, stream, x, y, out);
}

// Round 14
// 81.312 us; speedup vs baseline: 1.0304x; 1.0304x over previous
//
#include <hip/hip_runtime.h>

namespace {
constexpr int N_ = 8, C_ = 32, H_ = 256, W_ = 512, DISP_ = 25;
constexpr int CH = H_ * W_;   // elements between channels / disparities
constexpr int TILE = 256;     // output columns per block
constexpr int NSS = C_ / 2;   // 16 supersteps, 2 channels packed per step
constexpr int YST = 288;      // staged y cols: [tb-12, tb+276) covers needed [tb-12, tb+268)
constexpr int YOFF = 256;     // y region start (u32 units) inside a buffer
constexpr int BUF = 560;      // u32 stride per buffer (x 256 + y 288 + pad, mult of 16B)
}

typedef __attribute__((ext_vector_type(2))) _Float16 h2;

__device__ __forceinline__ h2 u2h(unsigned u) { return __builtin_bit_cast(h2, u); }
__device__ __forceinline__ unsigned h2u(h2 v) { return __builtin_bit_cast(unsigned, v); }

// Packed-f16 channel-pair kernel. Channels (2s,2s+1) are packed into one
// f16x2 per column at staging time (cvt_pkrtz); compute does
//   d = pk_sub(x2, y2); a = and(d, 0x7FFF7FFF); acc = v_dot2_f32_f16(a,1,acc)
// = 3 VALU per 2 channel-updates (vs 4 scalar-f32), acc stays f32 (precision:
// f16 input rounding ~1e-2/term, sum error ~0.05 << 1.31 threshold).
// One ds_read_b128 carries 4 cols x 2 channels -> LDS cycles halved vs r12.
//
// 256 threads/block = 256-col tile of one (n,h) row; grid = N*H*2.
//   tl = tid & 63 -> 4 output cols (w0l = 4*tl); g = tid>>6 -> disparity group
//   G0: i in [0,7) OFF +4 | G1: [7,13) OFF 0 | G2: [13,19) OFF -8 | G3: [19,25) OFF -12
//   window u32 index m = cw + 12 - i - OFF, compile-time in [0,12)
// Staging (all threads): x col tb+tid; y col tb-12+tid (+tid<32: tb+244+tid),
// clamped at image edges (garbage only feeds epilogue-zeroed outputs).
// Pipeline: load(s+1)->regs; compute(s) from LDS; cvt+write(s+1) to buf^1;
// __syncthreads. Loads get a full compute phase of latency slack; the
// barrier's vmcnt(0) is free (loads already consumed by the writes).
// Registers: acc 28 + win 16 + stage 6 + addr ~20 = ~72; (256,5) cap 102
// (margin 30; WRITE_SIZE is the spill tripwire).
template <int G>
__device__ __forceinline__ void body(const float* px, const float* py0,
                                     const float* py1, bool extra,
                                     float* __restrict__ op, unsigned* lds,
                                     int tid, int w0l, int w0g) {
  constexpr int I0 = (G == 0) ? 0 : (G == 1) ? 7 : (G == 2) ? 13 : 19;
  constexpr int NI = (G == 0) ? 7 : 6;
  constexpr int OFF = (G == 0) ? 4 : (G == 1) ? 0 : (G == 2) ? -8 : -12;

  const h2 one = {(_Float16)1.0f, (_Float16)1.0f};

  float acc[NI][4];
#pragma unroll
  for (int il = 0; il < NI; ++il)
#pragma unroll
    for (int cw = 0; cw < 4; ++cw) acc[il][cw] = 0.0f;

  float a0, a1, b0, b1, c0, c1;

#define SLOAD()                                                           \
  do {                                                                    \
    a0 = px[0]; a1 = px[CH];                                              \
    b0 = py0[0]; b1 = py0[CH];                                            \
    if (extra) { c0 = py1[0]; c1 = py1[CH]; }                             \
    px += 2 * CH; py0 += 2 * CH; py1 += 2 * CH;                           \
  } while (0)

#define SWRITE(bsel)                                                      \
  do {                                                                    \
    unsigned* wp = lds + (bsel)*BUF;                                      \
    h2 pa = __builtin_bit_cast(h2, __builtin_amdgcn_cvt_pkrtz(a0, a1));   \
    h2 pb = __builtin_bit_cast(h2, __builtin_amdgcn_cvt_pkrtz(b0, b1));   \
    wp[tid] = h2u(pa);                                                    \
    wp[YOFF + tid] = h2u(pb);                                             \
    if (extra) {                                                          \
      h2 pc = __builtin_bit_cast(h2, __builtin_amdgcn_cvt_pkrtz(c0, c1)); \
      wp[YOFF + 256 + tid] = h2u(pc);                                     \
    }                                                                     \
  } while (0)

#define COMPUTE(bsel)                                                     \
  do {                                                                    \
    const unsigned* bp = lds + (bsel)*BUF;                                \
    const uint4 xq = *reinterpret_cast<const uint4*>(bp + w0l);           \
    const uint4 q0 = *reinterpret_cast<const uint4*>(bp + YOFF + w0l +    \
                                                     (OFF + 12));         \
    const uint4 q1 = *reinterpret_cast<const uint4*>(bp + YOFF + w0l +    \
                                                     (OFF + 12) + 4);    \
    const uint4 q2 = *reinterpret_cast<const uint4*>(bp + YOFF + w0l +    \
                                                     (OFF + 12) + 8);    \
    const unsigned xs[4] = {xq.x, xq.y, xq.z, xq.w};                      \
    const unsigned yw[12] = {q0.x, q0.y, q0.z, q0.w, q1.x, q1.y, q1.z,    \
                             q1.w, q2.x, q2.y, q2.z, q2.w};               \
    _Pragma("unroll") for (int il = 0; il < NI; ++il) {                   \
      _Pragma("unroll") for (int cw = 0; cw < 4; ++cw) {                  \
        h2 d = u2h(xs[cw]) - u2h(yw[cw + 12 - (I0 + il) - OFF]);          \
        h2 a = u2h(h2u(d) & 0x7FFF7FFFu);                                 \
        acc[il][cw] = __builtin_amdgcn_fdot2(a, one, acc[il][cw], false); \
      }                                                                   \
    }                                                                     \
  } while (0)

  // Prologue: stage superstep 0 into buffer 0.
  SLOAD();
  SWRITE(0);
  __syncthreads();

  int cb = 0;
#pragma unroll 1
  for (int s = 0; s < NSS; ++s) {
    const bool more = (s + 1 < NSS);
    if (more) SLOAD();   // issue next superstep's global loads early
    COMPUTE(cb);         // ~200 cyc of compute hides the load latency
    if (more) SWRITE(cb ^ 1);
    __syncthreads();     // writes visible; buffer reuse ordered
    cb ^= 1;
  }

#undef SLOAD
#undef SWRITE
#undef COMPUTE

  // Epilogue: zero out-of-overlap (w,i) pairs, coalesced float4 stores.
#pragma unroll
  for (int il = 0; il < NI; ++il) {
    const int i = I0 + il;
    const int j0 = w0g - i + 12;  // y column used by cw=0
    float4 v;
    v.x = ((unsigned)(j0 + 0) < (unsigned)W_) ? acc[il][0] : 0.0f;
    v.y = ((unsigned)(j0 + 1) < (unsigned)W_) ? acc[il][1] : 0.0f;
    v.z = ((unsigned)(j0 + 2) < (unsigned)W_) ? acc[il][2] : 0.0f;
    v.w = ((unsigned)(j0 + 3) < (unsigned)W_) ? acc[il][3] : 0.0f;
    *reinterpret_cast<float4*>(op + (size_t)i * CH) = v;
  }
}

__global__ __launch_bounds__(256, 5) void rescost_kernel(
    const float* __restrict__ x, const float* __restrict__ y,
    float* __restrict__ out) {
  __shared__ __align__(16) unsigned lds[2 * BUF];  // 4480 B

  const int tid = threadIdx.x;
  const int tl = tid & 63;   // column group within tile
  const int g = tid >> 6;    // disparity group (wave-uniform)
  const int bid = blockIdx.x;
  const int tile = bid & 1;  // which 256-col half of the row
  const int r = bid >> 1;    // row in [0, N*H)
  const int n = r >> 8;      // H = 256
  const int h = r & (H_ - 1);
  const int tb = tile * TILE;
  const int w0l = tl << 2;
  const int w0g = tb + w0l;

  const size_t row_base = ((size_t)n * C_ * H_ + (size_t)h) * W_;

  // Staging columns (clamped at image edges; clamped values only reach
  // disparity outputs the epilogue zeroes).
  const int gx = tb + tid;
  int gy0 = tb - 12 + tid;
  gy0 = gy0 < 0 ? 0 : (gy0 > W_ - 1 ? W_ - 1 : gy0);
  int gy1 = tb - 12 + 256 + tid;
  gy1 = gy1 < 0 ? 0 : (gy1 > W_ - 1 ? W_ - 1 : gy1);
  const bool extra = tid < (YST - 256);  // 32 threads stage the y tail

  const float* px = x + row_base + gx;
  const float* py0 = y + row_base + gy0;
  const float* py1 = y + row_base + gy1;
  float* op = out + (size_t)n * DISP_ * CH + (size_t)h * W_ + w0g;

  if (g == 0)
    body<0>(px, py0, py1, extra, op, lds, tid, w0l, w0g);
  else if (g == 1)
    body<1>(px, py0, py1, extra, op, lds, tid, w0l, w0g);
  else if (g == 2)
    body<2>(px, py0, py1, extra, op, lds, tid, w0l, w0g);
  else
    body<3>(px, py0, py1, extra, op, lds, tid, w0l, w0g);
}

extern "C" void kernel_launch(void* const* d_in, const int* in_sizes, int n_in,
                              void* d_out, int out_size, void* d_ws, size_t ws_size,
                              hipStream_t stream) {
  const float* x = (const float*)d_in[0];
  const float* y = (const float*)d_in[1];
  float* out = (float*)d_out;
  dim3 grid(N_ * H_ * 2);  // 256-col tile per block
  dim3 block(256);
  hipLaunchKernelGGL(rescost_kernel, grid, block, 0, stream, x, y, out);
}